// Round 5
// baseline (452.844 us; speedup 1.0000x reference)
//
#include <hip/hip_runtime.h>
#include <math.h>

// Shapes (fixed by the problem)
#define B_   4
#define N_   16384
#define M_   4096
#define C1_  128
#define C2_  256
#define H_   256
#define K1_  384   // C1 + C2

#define NC_  8           // three_nn chunks over M  (DO NOT CHANGE: selection
#define MC_  (M_ / NC_)  //  dynamics are part of the verified numerics)
#define NB_  1024        // GEMM grid blocks (128 * 2 * 4) -> stats partials

typedef unsigned long long u64;
typedef __attribute__((ext_vector_type(8))) short bf16x8;   // 8 bf16 (4 VGPRs)
typedef __attribute__((ext_vector_type(4))) float f32x4;    // mfma acc

__device__ __forceinline__ unsigned short f2bf(float x) {
  unsigned u = __float_as_uint(x);
  return (unsigned short)((u + 0x7FFFu + ((u >> 16) & 1u)) >> 16);  // RNE
}
__device__ __forceinline__ float bf2f(unsigned short u) {
  return __uint_as_float((unsigned)u << 16);
}

// fp32-pair branchless insert (used only in the tiny merge kernel)
__device__ __forceinline__ void ins3(float cd, int ci,
                                     float& d1, int& i1,
                                     float& d2, int& i2,
                                     float& d3, int& i3) {
  bool p3 = cd < d3, p2 = cd < d2, p1 = cd < d1;
  float td = p1 ? d1 : cd; int ti = p1 ? i1 : ci;
  d1 = p1 ? cd : d1;       i1 = p1 ? ci : i1;
  float e3 = p2 ? d2 : cd; int e3i = p2 ? i2 : ci;
  d2 = p2 ? td : d2;       i2 = p2 ? ti : i2;
  d3 = p3 ? e3 : d3;       i3 = p3 ? e3i : i3;
}

// ---------------------------------------------------------------------------
// 1) transpose known_feats [B, C2, M] -> kfT [B, M, C2] fp32 (for gathers)
// ---------------------------------------------------------------------------
__global__ __launch_bounds__(256) void k_transpose(const float* __restrict__ kf,
                                                   float* __restrict__ kfT) {
  __shared__ float tile[32][33];
  int b  = blockIdx.z;
  int i0 = blockIdx.x * 32;
  int c0 = blockIdx.y * 32;
  int tx  = threadIdx.x & 31;
  int tyv = threadIdx.x >> 5;
  const float* src = kf + ((size_t)b * C2_ + c0) * M_ + i0;
  #pragma unroll
  for (int r = 0; r < 32; r += 8)
    tile[tyv + r][tx] = src[(size_t)(tyv + r) * M_ + tx];
  __syncthreads();
  float* dst = kfT + ((size_t)b * M_ + i0) * C2_ + c0;
  #pragma unroll
  for (int r = 0; r < 32; r += 8)
    dst[(size_t)(tyv + r) * C2_ + tx] = tile[tx][tyv + r];
}

// ---------------------------------------------------------------------------
// 2a) three_nn partials — 4 query points per lane, one ds_read per candidate.
//     SELECTION DYNAMICS ARE BIT-EXACT vs the verified baseline:
//       - subgroup g of a wave (lanes l, points j = jb + 64*g + l) is exactly
//         one baseline wave's lane set;
//       - each subgroup has its OWN guard __any(s_g < t3_g) computed from
//         exactly those 64 lanes -> identical fire/drop pattern;
//       - per-point insert sequence (ascending i, t3 update) unchanged;
//       - sk[] values, score chain fmaf(kx,ux,fmaf(ky,uy,fmaf(kz,uz,k2)))
//         and d = u2 + s unchanged -> identical bits everywhere.
//     The win: 1 ds_read_b128 feeds 4 points (LDS pipe was ~80% of the
//     kernel's critical path), loop control amortized 4x, 4-way ILP.
//     Fired-path min/fmed3 insert proven bit-exact on HW in R4.
// ---------------------------------------------------------------------------
__global__ __launch_bounds__(256) void k_three_nn_part(const float* __restrict__ unknown,
                                                       const float* __restrict__ known,
                                                       float* __restrict__ part_d,
                                                       int* __restrict__ part_i) {
  __shared__ float4 sk[MC_];
  int b    = blockIdx.y;
  int ch   = blockIdx.z;
  int base = ch * MC_;
  const float* kb = known + ((size_t)b * M_ + base) * 3;
  for (int i = threadIdx.x; i < MC_; i += 256) {
    float x = kb[3*i+0], y = kb[3*i+1], z = kb[3*i+2];
    sk[i] = make_float4(-2.0f*x, -2.0f*y, -2.0f*z, x*x + y*y + z*z);
  }
  __syncthreads();

  int wv = threadIdx.x >> 6, lane = threadIdx.x & 63;
  int jb = blockIdx.x * 1024 + wv * 256 + lane;   // subgroup g: j = jb + 64*g

  const float INF = __builtin_inff();
  float ux[4], uy[4], uz[4], u2[4];
  float d1[4], d2[4], d3[4], t3[4];
  int   i1[4], i2[4], i3[4];
  #pragma unroll
  for (int g = 0; g < 4; ++g) {
    const float* up = unknown + ((size_t)b * N_ + jb + 64*g) * 3;
    ux[g] = up[0]; uy[g] = up[1]; uz[g] = up[2];
    u2[g] = ux[g]*ux[g] + uy[g]*uy[g] + uz[g]*uz[g];
    d1[g] = INF; d2[g] = INF; d3[g] = INF; t3[g] = INF;
    i1[g] = 0; i2[g] = 0; i3[g] = 0;
  }

  #pragma unroll 2
  for (int i = 0; i < MC_; ++i) {
    float4 k = sk[i];
    int gi = base + i;
    #pragma unroll
    for (int g = 0; g < 4; ++g) {
      float s = fmaf(k.x, ux[g], fmaf(k.y, uy[g], fmaf(k.z, uz[g], k.w)));
      if (__any(s < t3[g])) {                 // subgroup-g guard == baseline wave
        float d = u2[g] + s;
        bool p3 = d < d3[g], p2 = d < d2[g], p1 = d < d1[g];
        int ni1 = p1 ? gi    : i1[g];
        int ni2 = p1 ? i1[g] : (p2 ? gi : i2[g]);
        int ni3 = p2 ? i2[g] : (p3 ? gi : i3[g]);
        float od1 = d1[g], od2 = d2[g], od3 = d3[g];
        d1[g] = fminf(d, od1);
        d2[g] = __builtin_amdgcn_fmed3f(d, od1, od2);
        d3[g] = __builtin_amdgcn_fmed3f(d, od2, od3);
        i1[g] = ni1; i2[g] = ni2; i3[g] = ni3;
        t3[g] = d3[g] - u2[g];
      }
    }
  }
  #pragma unroll
  for (int g = 0; g < 4; ++g) {
    size_t o = ((size_t)(ch * B_ + b) * 3) * N_ + jb + 64*g;
    part_d[o] = d1[g]; part_d[o + N_] = d2[g]; part_d[o + 2*(size_t)N_] = d3[g];
    part_i[o] = i1[g]; part_i[o + N_] = i2[g]; part_i[o + 2*(size_t)N_] = i3[g];
  }
}

// ---------------------------------------------------------------------------
// 2b) merge NC partial top-3 lists -> final idx + inverse-distance weights.
// ---------------------------------------------------------------------------
__global__ __launch_bounds__(256) void k_three_merge(const float* __restrict__ part_d,
                                                     const int* __restrict__ part_i,
                                                     int* __restrict__ idx_o,
                                                     float* __restrict__ w_o) {
  int j = blockIdx.x * 256 + threadIdx.x;
  int b = blockIdx.y;
  size_t o0 = ((size_t)b * 3) * N_ + j;
  float d1 = part_d[o0], d2 = part_d[o0 + N_], d3 = part_d[o0 + 2*(size_t)N_];
  int   i1 = part_i[o0], i2 = part_i[o0 + N_], i3 = part_i[o0 + 2*(size_t)N_];
  #pragma unroll
  for (int c = 1; c < NC_; ++c) {
    size_t oc = ((size_t)(c * B_ + b) * 3) * N_ + j;
    #pragma unroll
    for (int k = 0; k < 3; ++k) {
      float cd = part_d[oc + (size_t)k * N_];
      int   ci = part_i[oc + (size_t)k * N_];
      ins3(cd, ci, d1, i1, d2, i2, d3, i3);
    }
  }
  float r1 = 1.0f / (d1 + 1e-8f);
  float r2 = 1.0f / (d2 + 1e-8f);
  float r3 = 1.0f / (d3 + 1e-8f);
  float s  = r1 + r2 + r3;
  size_t o = ((size_t)b * N_ + j) * 3;
  idx_o[o+0] = i1; idx_o[o+1] = i2; idx_o[o+2] = i3;
  w_o[o+0] = r1 / s; w_o[o+1] = r2 / s; w_o[o+2] = r3 / s;
}

// ---------------------------------------------------------------------------
// 3a) three_interpolate -> Xb1[b][j][0:256] bf16 (point-major GEMM operand)
// ---------------------------------------------------------------------------
#define IP_ 32
__global__ __launch_bounds__(256) void k_interp(const float* __restrict__ kfT,
                                                const int* __restrict__ idx,
                                                const float* __restrict__ wgt,
                                                unsigned short* __restrict__ Xb1) {
  int b  = blockIdx.y;
  int j0 = blockIdx.x * IP_;
  const float* kb = kfT + (size_t)b * M_ * C2_;
  int c = threadIdx.x;
  for (int p = 0; p < IP_; ++p) {
    size_t pj = ((size_t)b * N_ + j0 + p) * 3;   // uniform -> scalar loads
    int   i0 = idx[pj+0], i1 = idx[pj+1], i2 = idx[pj+2];
    float w0 = wgt[pj+0], w1 = wgt[pj+1], w2 = wgt[pj+2];
    float v = w0 * kb[(size_t)i0 * C2_ + c]
            + w1 * kb[(size_t)i1 * C2_ + c]
            + w2 * kb[(size_t)i2 * C2_ + c];
    Xb1[((size_t)b * N_ + j0 + p) * K1_ + c] = f2bf(v);
  }
}

// ---------------------------------------------------------------------------
// 3b) transpose+cast unknown_feats [B,C1,N] fp32 -> Xb1[b][j][256+c] bf16
// ---------------------------------------------------------------------------
__global__ __launch_bounds__(256) void k_uf_t(const float* __restrict__ uf,
                                              unsigned short* __restrict__ Xb1) {
  __shared__ float tile[32][33];
  int b  = blockIdx.z;
  int j0 = blockIdx.x * 32;
  int c0 = blockIdx.y * 32;
  int tx = threadIdx.x & 31, ty = threadIdx.x >> 5;
  const float* src = uf + ((size_t)b * C1_ + c0) * N_ + j0;
  #pragma unroll
  for (int r = 0; r < 32; r += 8)
    tile[ty + r][tx] = src[(size_t)(ty + r) * N_ + tx];
  __syncthreads();
  unsigned short* dst = Xb1 + ((size_t)b * N_ + j0) * K1_ + C2_ + c0;
  #pragma unroll
  for (int r = 0; r < 32; r += 8)
    dst[(size_t)(ty + r) * K1_ + tx] = f2bf(tile[tx][ty + r]);
}

// ---------------------------------------------------------------------------
// 3c) cast both weight matrices to bf16 (fused, contiguous dst)
// ---------------------------------------------------------------------------
__global__ void k_wcast(const float* __restrict__ W1, const float* __restrict__ W2,
                        unsigned short* __restrict__ Wb) {
  int i = blockIdx.x * 256 + threadIdx.x;
  int n1 = H_ * K1_, nt = n1 + H_ * H_;
  if (i < nt) Wb[i] = f2bf(i < n1 ? W1[i] : W2[i - n1]);
}

// ---------------------------------------------------------------------------
// 4) bf16 MFMA GEMM, NO LDS staging, NO K-loop barriers (R4 structure).
//    OUTL 0: write h[b][n][m] bf16 (point-major, feeds bn_relu_cast)
//    OUTL 1: write out[b][m][n] fp32 (final layout)
// ---------------------------------------------------------------------------
template <int K, int OUTL>
__global__ __launch_bounds__(256) void k_gemm_mfma(const unsigned short* __restrict__ Wb,
                                                   const unsigned short* __restrict__ Xb,
                                                   float* __restrict__ outp,
                                                   float* __restrict__ stats_p) {
  __shared__ float sred[256];     // [0:128) sum, [128:256) sumsq for this m-tile
  int t = threadIdx.x;
  sred[t] = 0.0f;
  __syncthreads();

  int b  = blockIdx.z;
  int m0 = blockIdx.y * 128;
  int j0 = blockIdx.x * 128;
  int wid = t >> 6, lane = t & 63;
  int wr = wid >> 1, wc = wid & 1;          // wave quadrant (m, n)
  int l15 = lane & 15, quad = lane >> 4;

  const unsigned short* aptr = Wb + (size_t)(m0 + 64*wr + l15) * K + quad * 8;
  const unsigned short* bptr = Xb + ((size_t)b * N_ + j0 + 64*wc + l15) * K + quad * 8;

  f32x4 acc[4][4] = {};
  for (int kt = 0; kt < K; kt += 32) {
    bf16x8 af[4], bfr[4];
    #pragma unroll
    for (int i = 0; i < 4; ++i)
      af[i] = *(const bf16x8*)(aptr + (size_t)(16*i) * K + kt);
    #pragma unroll
    for (int i = 0; i < 4; ++i)
      bfr[i] = *(const bf16x8*)(bptr + (size_t)(16*i) * K + kt);
    #pragma unroll
    for (int im = 0; im < 4; ++im)
      #pragma unroll
      for (int in = 0; in < 4; ++in)
        acc[im][in] = __builtin_amdgcn_mfma_f32_16x16x32_bf16(af[im], bfr[in], acc[im][in], 0, 0, 0);
  }

  // --- BN statistics: shuffle-reduce over 16 n-lanes, combine in LDS ---
  #pragma unroll
  for (int im = 0; im < 4; ++im) {
    #pragma unroll
    for (int r = 0; r < 4; ++r) {
      float sv = 0.f, qv = 0.f;
      #pragma unroll
      for (int in = 0; in < 4; ++in) { float v = acc[im][in][r]; sv += v; qv += v * v; }
      #pragma unroll
      for (int off = 1; off < 16; off <<= 1) {
        sv += __shfl_xor(sv, off, 64);
        qv += __shfl_xor(qv, off, 64);
      }
      if (l15 == 0) {
        int ml = 64*wr + 16*im + 4*quad + r;   // 0..127 within tile
        atomicAdd(&sred[ml], sv);              // LDS atomic, 2-way at most
        atomicAdd(&sred[128 + ml], qv);
      }
    }
  }
  __syncthreads();
  if (t < 128) {
    int bid = (blockIdx.z * gridDim.y + blockIdx.y) * gridDim.x + blockIdx.x;
    stats_p[(size_t)(m0 + t) * NB_ + bid]       = sred[t];
    stats_p[(size_t)(256 + m0 + t) * NB_ + bid] = sred[128 + t];
  }

  // --- store ---
  if (OUTL == 0) {
    unsigned short* hp = (unsigned short*)outp;   // h bf16 [b][n][256]
    #pragma unroll
    for (int in = 0; in < 4; ++in) {
      size_t nrow = (size_t)b * N_ + j0 + 64*wc + 16*in + l15;
      unsigned short* p = hp + nrow * 256 + m0 + 64*wr + quad * 4;
      #pragma unroll
      for (int im = 0; im < 4; ++im) {
        ushort4 o;
        o.x = f2bf(acc[im][in][0]); o.y = f2bf(acc[im][in][1]);
        o.z = f2bf(acc[im][in][2]); o.w = f2bf(acc[im][in][3]);
        *(ushort4*)(p + 16 * im) = o;
      }
    }
  } else {
    #pragma unroll
    for (int im = 0; im < 4; ++im)
      #pragma unroll
      for (int r = 0; r < 4; ++r) {
        int m = m0 + 64*wr + 16*im + 4*quad + r;
        size_t base = ((size_t)b * 256 + m) * N_ + j0 + 64*wc + l15;
        #pragma unroll
        for (int in = 0; in < 4; ++in)
          outp[base + 16 * in] = acc[im][in][r];
      }
  }
}

// ---------------------------------------------------------------------------
// 5) reduce per-block stats partials -> bnp (scale/shift). One block per channel.
// ---------------------------------------------------------------------------
__global__ __launch_bounds__(256) void k_reduce_bn(const float* __restrict__ sp,
                                                   const float* __restrict__ gamma,
                                                   const float* __restrict__ beta,
                                                   float* __restrict__ bnp) {
  int c = blockIdx.x;        // 0..255
  int t = threadIdx.x;
  float s = 0.f, q = 0.f;
  for (int i = t; i < NB_; i += 256) {
    s += sp[(size_t)c * NB_ + i];
    q += sp[(size_t)(256 + c) * NB_ + i];
  }
  #pragma unroll
  for (int off = 32; off >= 1; off >>= 1) {
    s += __shfl_down(s, off, 64);
    q += __shfl_down(q, off, 64);
  }
  __shared__ float ss[4], qq[4];
  if ((t & 63) == 0) { ss[t >> 6] = s; qq[t >> 6] = q; }
  __syncthreads();
  if (t == 0) {
    s = ss[0] + ss[1] + ss[2] + ss[3];
    q = qq[0] + qq[1] + qq[2] + qq[3];
    const float inv = 1.0f / (float)(B_ * N_);
    float mean = s * inv;
    float var  = q * inv - mean * mean;
    float sc = gamma[c] / sqrtf(var + 1e-5f);
    bnp[c] = sc;
    bnp[256 + c] = beta[c] - mean * sc;
  }
}

// ---------------------------------------------------------------------------
// 6) bn1 + relu: h[b][n][256] bf16 -> Xb2[b][n][256] bf16
// ---------------------------------------------------------------------------
__global__ __launch_bounds__(256) void k_bn_relu_cast(const unsigned short* __restrict__ h,
                                                      const float* __restrict__ bnp,
                                                      unsigned short* __restrict__ Xb2) {
  size_t e = (size_t)blockIdx.x * 256 + threadIdx.x;   // ushort4 index
  ushort4 v = ((const ushort4*)h)[e];
  int c0 = (int)((e & 63) << 2);                       // 64 ushort4 per point-row
  float4 sc = *(const float4*)(bnp + c0);
  float4 sh = *(const float4*)(bnp + 256 + c0);
  ushort4 o;
  o.x = f2bf(fmaxf(fmaf(sc.x, bf2f(v.x), sh.x), 0.0f));
  o.y = f2bf(fmaxf(fmaf(sc.y, bf2f(v.y), sh.y), 0.0f));
  o.z = f2bf(fmaxf(fmaf(sc.z, bf2f(v.z), sh.z), 0.0f));
  o.w = f2bf(fmaxf(fmaf(sc.w, bf2f(v.w), sh.w), 0.0f));
  ((ushort4*)Xb2)[e] = o;
}

// ---------------------------------------------------------------------------
// 7) final BN + ReLU in place on d_out [B][H][N]
// ---------------------------------------------------------------------------
__global__ __launch_bounds__(256) void k_bn_relu(float* __restrict__ out,
                                                 const float* __restrict__ bnp) {
  size_t e = (size_t)blockIdx.x * 256 + threadIdx.x;
  float4 v = ((float4*)out)[e];
  int c = (int)((e >> 12) & 255);
  float sc = bnp[c], sh = bnp[256 + c];
  v.x = fmaxf(fmaf(sc, v.x, sh), 0.0f);
  v.y = fmaxf(fmaf(sc, v.y, sh), 0.0f);
  v.z = fmaxf(fmaf(sc, v.z, sh), 0.0f);
  v.w = fmaxf(fmaf(sc, v.w, sh), 0.0f);
  ((float4*)out)[e] = v;
}

// ---------------------------------------------------------------------------
extern "C" void kernel_launch(void* const* d_in, const int* in_sizes, int n_in,
                              void* d_out, int out_size, void* d_ws, size_t ws_size,
                              hipStream_t stream) {
  const float* unknown = (const float*)d_in[0];
  const float* known   = (const float*)d_in[1];
  const float* uf      = (const float*)d_in[2];
  const float* kf      = (const float*)d_in[3];
  const float* W1      = (const float*)d_in[4];
  const float* g1      = (const float*)d_in[5];
  const float* b1      = (const float*)d_in[6];
  const float* W2      = (const float*)d_in[7];
  const float* g2      = (const float*)d_in[8];
  const float* b2      = (const float*)d_in[9];
  float* out = (float*)d_out;

  // workspace layout (~71 MB):
  //   kfT     : B*M*C2 fp32 = 16.8 MB
  //   Xb1     : B*N*K1 bf16 = 48 MB   (alias: part_d/part_i early, Xb2 late)
  //   idx/wgt : 1.6 MB ; Wb : 0.33 MB ; stats_p : 2 MB
  // h (B*N*H bf16, 32 MB) lives in d_out until GEMM2 overwrites it.
  float* ws = (float*)d_ws;
  float*          kfT  = ws;                                          // 4194304 f
  unsigned short* Xb1  = (unsigned short*)(kfT + (size_t)B_*M_*C2_);  // 25165824 us
  float*          part_d = (float*)Xb1;                               // alias (early)
  int*            part_i = (int*)(part_d + (size_t)NC_*B_*3*N_);      // 6.3 MB each
  unsigned short* Xb2  = Xb1;                                         // alias (late)
  int*   idx    = (int*)(Xb1 + (size_t)B_*N_*K1_);
  float* wgt    = (float*)(idx + (size_t)B_*N_*3);
  unsigned short* W1b = (unsigned short*)(wgt + (size_t)B_*N_*3);     // 98304 us
  unsigned short* W2b = W1b + H_*K1_;                                 // 65536 us
  float* stats_p = (float*)(W2b + H_*H_);                             // 524288 f
  float* bnp1   = stats_p + 512 * NB_;
  float* bnp2   = bnp1 + 512;
  float* h      = out;                                                // d_out scratch (bf16)

  k_wcast<<<(H_*K1_ + H_*H_ + 255)/256, 256, 0, stream>>>(W1, W2, W1b);
  k_transpose<<<dim3(M_/32, C2_/32, B_), 256, 0, stream>>>(kf, kfT);
  k_three_nn_part<<<dim3(N_/1024, B_, NC_), 256, 0, stream>>>(unknown, known, part_d, part_i);
  k_three_merge<<<dim3(N_/256, B_), 256, 0, stream>>>(part_d, part_i, idx, wgt);
  k_interp<<<dim3(N_/IP_, B_), 256, 0, stream>>>(kfT, idx, wgt, Xb1);
  k_uf_t<<<dim3(N_/32, C1_/32, B_), 256, 0, stream>>>(uf, Xb1);
  k_gemm_mfma<K1_, 0><<<dim3(N_/128, 2, B_), 256, 0, stream>>>(W1b, Xb1, h, stats_p);
  k_reduce_bn<<<256, 256, 0, stream>>>(stats_p, g1, b1, bnp1);
  k_bn_relu_cast<<<(int)((size_t)B_*N_*H_/4/256), 256, 0, stream>>>((unsigned short*)h, bnp1, Xb2);
  k_gemm_mfma<H_, 1><<<dim3(N_/128, 2, B_), 256, 0, stream>>>(W2b, Xb2, out, stats_p);
  k_reduce_bn<<<256, 256, 0, stream>>>(stats_p, g2, b2, bnp2);
  k_bn_relu<<<(int)((size_t)B_*H_*N_/4/256), 256, 0, stream>>>(out, bnp2);
}

// Round 6
// 443.423 us; speedup vs baseline: 1.0212x; 1.0212x over previous
//
#include <hip/hip_runtime.h>
#include <math.h>

// Shapes (fixed by the problem)
#define B_   4
#define N_   16384
#define M_   4096
#define C1_  128
#define C2_  256
#define H_   256
#define K1_  384   // C1 + C2

#define NC_  8           // three_nn chunks over M  (DO NOT CHANGE: selection
#define MC_  (M_ / NC_)  //  dynamics are part of the verified numerics)
#define NB_  1024        // GEMM grid blocks (128 * 2 * 4) -> stats partials

typedef unsigned long long u64;
typedef __attribute__((ext_vector_type(8))) short bf16x8;   // 8 bf16 (4 VGPRs)
typedef __attribute__((ext_vector_type(4))) float f32x4;    // mfma acc

__device__ __forceinline__ unsigned short f2bf(float x) {
  unsigned u = __float_as_uint(x);
  return (unsigned short)((u + 0x7FFFu + ((u >> 16) & 1u)) >> 16);  // RNE
}
__device__ __forceinline__ float bf2f(unsigned short u) {
  return __uint_as_float((unsigned)u << 16);
}

// fp32-pair branchless insert (used only in the tiny merge kernel)
__device__ __forceinline__ void ins3(float cd, int ci,
                                     float& d1, int& i1,
                                     float& d2, int& i2,
                                     float& d3, int& i3) {
  bool p3 = cd < d3, p2 = cd < d2, p1 = cd < d1;
  float td = p1 ? d1 : cd; int ti = p1 ? i1 : ci;
  d1 = p1 ? cd : d1;       i1 = p1 ? ci : i1;
  float e3 = p2 ? d2 : cd; int e3i = p2 ? i2 : ci;
  d2 = p2 ? td : d2;       i2 = p2 ? ti : i2;
  d3 = p3 ? e3 : d3;       i3 = p3 ? e3i : i3;
}

// ---------------------------------------------------------------------------
// 1) transpose known_feats [B, C2, M] -> kfT [B, M, C2] fp32 (for gathers)
// ---------------------------------------------------------------------------
__global__ __launch_bounds__(256) void k_transpose(const float* __restrict__ kf,
                                                   float* __restrict__ kfT) {
  __shared__ float tile[32][33];
  int b  = blockIdx.z;
  int i0 = blockIdx.x * 32;
  int c0 = blockIdx.y * 32;
  int tx  = threadIdx.x & 31;
  int tyv = threadIdx.x >> 5;
  const float* src = kf + ((size_t)b * C2_ + c0) * M_ + i0;
  #pragma unroll
  for (int r = 0; r < 32; r += 8)
    tile[tyv + r][tx] = src[(size_t)(tyv + r) * M_ + tx];
  __syncthreads();
  float* dst = kfT + ((size_t)b * M_ + i0) * C2_ + c0;
  #pragma unroll
  for (int r = 0; r < 32; r += 8)
    dst[(size_t)(tyv + r) * C2_ + tx] = tile[tx][tyv + r];
}

// ---------------------------------------------------------------------------
// 2a) three_nn partials — BRANCHLESS, 2 query points per lane.
//     SELECTION DYNAMICS ARE BIT-EXACT vs the verified R4 baseline:
//       - subgroup g (lanes l, points j = jb + 64*g + l) is exactly one
//         baseline wave's lane set; its guard __any(s_g < t3_g) ballots over
//         exactly those 64 lanes (multipoint scheme HW-proven exact in R5);
//       - t3 == fl(d3 - u2) is an invariant of the baseline (d3 only changes
//         where t3 is recomputed), so recomputing it every iteration is
//         bit-identical;
//       - the fired-path insert is replaced by an UNCONDITIONAL insert of
//         dg = wf ? d : +INF.  Inserting +INF is a no-op through the
//         fminf/fmed3/select network (fminf(INF,d1)=d1, fmed3(INF,d1,d2)=d2,
//         all predicates false), and the fmed3 value-update was HW-proven
//         bit-exact in R4.  So the fire/drop pattern -- including the
//         1-ulp t3 miss window the reference comparison depends on -- is
//         reproduced exactly, with no divergent branch.
//     Why: R4/R5 counters proved the kernel is VALU-ISSUE-bound (~30 eff.
//     insts/candidate from the 74%-fire branchy insert + branch overhead).
//     Branchless is ~18 VALU/candidate-point; ballot/gi run on SALU.
//     2 pts/lane halves the ds_read_b128 stream (CU-shared pipe) and loop
//     overhead; 1024 blocks = 4 waves/SIMD, enough for issue saturation
//     with 2 independent insert chains per wave (R5's cliff was 2 waves/SIMD
//     + branch serialization).
// ---------------------------------------------------------------------------
__global__ __launch_bounds__(256) void k_three_nn_part(const float* __restrict__ unknown,
                                                       const float* __restrict__ known,
                                                       float* __restrict__ part_d,
                                                       int* __restrict__ part_i) {
  __shared__ float4 sk[MC_];
  int b    = blockIdx.y;
  int ch   = blockIdx.z;
  int base = ch * MC_;
  const float* kb = known + ((size_t)b * M_ + base) * 3;
  for (int i = threadIdx.x; i < MC_; i += 256) {
    float x = kb[3*i+0], y = kb[3*i+1], z = kb[3*i+2];
    sk[i] = make_float4(-2.0f*x, -2.0f*y, -2.0f*z, x*x + y*y + z*z);
  }
  __syncthreads();

  int wv = threadIdx.x >> 6, lane = threadIdx.x & 63;
  int jb = blockIdx.x * 512 + wv * 128 + lane;   // subgroup g: j = jb + 64*g

  const float INF = __builtin_inff();
  float ux[2], uy[2], uz[2], u2[2];
  float d1[2], d2[2], d3[2];
  int   i1[2], i2[2], i3[2];
  #pragma unroll
  for (int g = 0; g < 2; ++g) {
    const float* up = unknown + ((size_t)b * N_ + jb + 64*g) * 3;
    ux[g] = up[0]; uy[g] = up[1]; uz[g] = up[2];
    u2[g] = ux[g]*ux[g] + uy[g]*uy[g] + uz[g]*uz[g];
    d1[g] = INF; d2[g] = INF; d3[g] = INF;
    i1[g] = 0; i2[g] = 0; i3[g] = 0;
  }

  #pragma unroll 4
  for (int i = 0; i < MC_; ++i) {
    float4 k = sk[i];
    int gi = base + i;
    #pragma unroll
    for (int g = 0; g < 2; ++g) {
      float s  = fmaf(k.x, ux[g], fmaf(k.y, uy[g], fmaf(k.z, uz[g], k.w)));
      float t3 = d3[g] - u2[g];              // invariant: == baseline t3
      float d  = u2[g] + s;
      bool  wf = __any(s < t3);              // subgroup-g guard == baseline
      float dg = wf ? d : INF;               // INF insert == no-op
      bool p1 = dg < d1[g], p2 = dg < d2[g], p3 = dg < d3[g];
      int ni1 = p1 ? gi    : i1[g];
      int ni2 = p1 ? i1[g] : (p2 ? gi : i2[g]);
      int ni3 = p2 ? i2[g] : (p3 ? gi : i3[g]);
      float od1 = d1[g], od2 = d2[g], od3 = d3[g];
      d1[g] = fminf(dg, od1);
      d2[g] = __builtin_amdgcn_fmed3f(dg, od1, od2);
      d3[g] = __builtin_amdgcn_fmed3f(dg, od2, od3);
      i1[g] = ni1; i2[g] = ni2; i3[g] = ni3;
    }
  }
  #pragma unroll
  for (int g = 0; g < 2; ++g) {
    size_t o = ((size_t)(ch * B_ + b) * 3) * N_ + jb + 64*g;
    part_d[o] = d1[g]; part_d[o + N_] = d2[g]; part_d[o + 2*(size_t)N_] = d3[g];
    part_i[o] = i1[g]; part_i[o + N_] = i2[g]; part_i[o + 2*(size_t)N_] = i3[g];
  }
}

// ---------------------------------------------------------------------------
// 2b) merge NC partial top-3 lists -> final idx + inverse-distance weights.
// ---------------------------------------------------------------------------
__global__ __launch_bounds__(256) void k_three_merge(const float* __restrict__ part_d,
                                                     const int* __restrict__ part_i,
                                                     int* __restrict__ idx_o,
                                                     float* __restrict__ w_o) {
  int j = blockIdx.x * 256 + threadIdx.x;
  int b = blockIdx.y;
  size_t o0 = ((size_t)b * 3) * N_ + j;
  float d1 = part_d[o0], d2 = part_d[o0 + N_], d3 = part_d[o0 + 2*(size_t)N_];
  int   i1 = part_i[o0], i2 = part_i[o0 + N_], i3 = part_i[o0 + 2*(size_t)N_];
  #pragma unroll
  for (int c = 1; c < NC_; ++c) {
    size_t oc = ((size_t)(c * B_ + b) * 3) * N_ + j;
    #pragma unroll
    for (int k = 0; k < 3; ++k) {
      float cd = part_d[oc + (size_t)k * N_];
      int   ci = part_i[oc + (size_t)k * N_];
      ins3(cd, ci, d1, i1, d2, i2, d3, i3);
    }
  }
  float r1 = 1.0f / (d1 + 1e-8f);
  float r2 = 1.0f / (d2 + 1e-8f);
  float r3 = 1.0f / (d3 + 1e-8f);
  float s  = r1 + r2 + r3;
  size_t o = ((size_t)b * N_ + j) * 3;
  idx_o[o+0] = i1; idx_o[o+1] = i2; idx_o[o+2] = i3;
  w_o[o+0] = r1 / s; w_o[o+1] = r2 / s; w_o[o+2] = r3 / s;
}

// ---------------------------------------------------------------------------
// 3a) three_interpolate -> Xb1[b][j][0:256] bf16 (point-major GEMM operand)
// ---------------------------------------------------------------------------
#define IP_ 32
__global__ __launch_bounds__(256) void k_interp(const float* __restrict__ kfT,
                                                const int* __restrict__ idx,
                                                const float* __restrict__ wgt,
                                                unsigned short* __restrict__ Xb1) {
  int b  = blockIdx.y;
  int j0 = blockIdx.x * IP_;
  const float* kb = kfT + (size_t)b * M_ * C2_;
  int c = threadIdx.x;
  for (int p = 0; p < IP_; ++p) {
    size_t pj = ((size_t)b * N_ + j0 + p) * 3;   // uniform -> scalar loads
    int   i0 = idx[pj+0], i1 = idx[pj+1], i2 = idx[pj+2];
    float w0 = wgt[pj+0], w1 = wgt[pj+1], w2 = wgt[pj+2];
    float v = w0 * kb[(size_t)i0 * C2_ + c]
            + w1 * kb[(size_t)i1 * C2_ + c]
            + w2 * kb[(size_t)i2 * C2_ + c];
    Xb1[((size_t)b * N_ + j0 + p) * K1_ + c] = f2bf(v);
  }
}

// ---------------------------------------------------------------------------
// 3b) transpose+cast unknown_feats [B,C1,N] fp32 -> Xb1[b][j][256+c] bf16
// ---------------------------------------------------------------------------
__global__ __launch_bounds__(256) void k_uf_t(const float* __restrict__ uf,
                                              unsigned short* __restrict__ Xb1) {
  __shared__ float tile[32][33];
  int b  = blockIdx.z;
  int j0 = blockIdx.x * 32;
  int c0 = blockIdx.y * 32;
  int tx = threadIdx.x & 31, ty = threadIdx.x >> 5;
  const float* src = uf + ((size_t)b * C1_ + c0) * N_ + j0;
  #pragma unroll
  for (int r = 0; r < 32; r += 8)
    tile[ty + r][tx] = src[(size_t)(ty + r) * N_ + tx];
  __syncthreads();
  unsigned short* dst = Xb1 + ((size_t)b * N_ + j0) * K1_ + C2_ + c0;
  #pragma unroll
  for (int r = 0; r < 32; r += 8)
    dst[(size_t)(ty + r) * K1_ + tx] = f2bf(tile[tx][ty + r]);
}

// ---------------------------------------------------------------------------
// 3c) cast both weight matrices to bf16 (fused, contiguous dst)
// ---------------------------------------------------------------------------
__global__ void k_wcast(const float* __restrict__ W1, const float* __restrict__ W2,
                        unsigned short* __restrict__ Wb) {
  int i = blockIdx.x * 256 + threadIdx.x;
  int n1 = H_ * K1_, nt = n1 + H_ * H_;
  if (i < nt) Wb[i] = f2bf(i < n1 ? W1[i] : W2[i - n1]);
}

// ---------------------------------------------------------------------------
// 4) bf16 MFMA GEMM, NO LDS staging, NO K-loop barriers (R4 structure).
//    OUTL 0: write h[b][n][m] bf16 (point-major, feeds bn_relu_cast)
//    OUTL 1: write out[b][m][n] fp32 (final layout)
// ---------------------------------------------------------------------------
template <int K, int OUTL>
__global__ __launch_bounds__(256) void k_gemm_mfma(const unsigned short* __restrict__ Wb,
                                                   const unsigned short* __restrict__ Xb,
                                                   float* __restrict__ outp,
                                                   float* __restrict__ stats_p) {
  __shared__ float sred[256];     // [0:128) sum, [128:256) sumsq for this m-tile
  int t = threadIdx.x;
  sred[t] = 0.0f;
  __syncthreads();

  int b  = blockIdx.z;
  int m0 = blockIdx.y * 128;
  int j0 = blockIdx.x * 128;
  int wid = t >> 6, lane = t & 63;
  int wr = wid >> 1, wc = wid & 1;          // wave quadrant (m, n)
  int l15 = lane & 15, quad = lane >> 4;

  const unsigned short* aptr = Wb + (size_t)(m0 + 64*wr + l15) * K + quad * 8;
  const unsigned short* bptr = Xb + ((size_t)b * N_ + j0 + 64*wc + l15) * K + quad * 8;

  f32x4 acc[4][4] = {};
  for (int kt = 0; kt < K; kt += 32) {
    bf16x8 af[4], bfr[4];
    #pragma unroll
    for (int i = 0; i < 4; ++i)
      af[i] = *(const bf16x8*)(aptr + (size_t)(16*i) * K + kt);
    #pragma unroll
    for (int i = 0; i < 4; ++i)
      bfr[i] = *(const bf16x8*)(bptr + (size_t)(16*i) * K + kt);
    #pragma unroll
    for (int im = 0; im < 4; ++im)
      #pragma unroll
      for (int in = 0; in < 4; ++in)
        acc[im][in] = __builtin_amdgcn_mfma_f32_16x16x32_bf16(af[im], bfr[in], acc[im][in], 0, 0, 0);
  }

  // --- BN statistics: shuffle-reduce over 16 n-lanes, combine in LDS ---
  #pragma unroll
  for (int im = 0; im < 4; ++im) {
    #pragma unroll
    for (int r = 0; r < 4; ++r) {
      float sv = 0.f, qv = 0.f;
      #pragma unroll
      for (int in = 0; in < 4; ++in) { float v = acc[im][in][r]; sv += v; qv += v * v; }
      #pragma unroll
      for (int off = 1; off < 16; off <<= 1) {
        sv += __shfl_xor(sv, off, 64);
        qv += __shfl_xor(qv, off, 64);
      }
      if (l15 == 0) {
        int ml = 64*wr + 16*im + 4*quad + r;   // 0..127 within tile
        atomicAdd(&sred[ml], sv);              // LDS atomic, 2-way at most
        atomicAdd(&sred[128 + ml], qv);
      }
    }
  }
  __syncthreads();
  if (t < 128) {
    int bid = (blockIdx.z * gridDim.y + blockIdx.y) * gridDim.x + blockIdx.x;
    stats_p[(size_t)(m0 + t) * NB_ + bid]       = sred[t];
    stats_p[(size_t)(256 + m0 + t) * NB_ + bid] = sred[128 + t];
  }

  // --- store ---
  if (OUTL == 0) {
    unsigned short* hp = (unsigned short*)outp;   // h bf16 [b][n][256]
    #pragma unroll
    for (int in = 0; in < 4; ++in) {
      size_t nrow = (size_t)b * N_ + j0 + 64*wc + 16*in + l15;
      unsigned short* p = hp + nrow * 256 + m0 + 64*wr + quad * 4;
      #pragma unroll
      for (int im = 0; im < 4; ++im) {
        ushort4 o;
        o.x = f2bf(acc[im][in][0]); o.y = f2bf(acc[im][in][1]);
        o.z = f2bf(acc[im][in][2]); o.w = f2bf(acc[im][in][3]);
        *(ushort4*)(p + 16 * im) = o;
      }
    }
  } else {
    #pragma unroll
    for (int im = 0; im < 4; ++im)
      #pragma unroll
      for (int r = 0; r < 4; ++r) {
        int m = m0 + 64*wr + 16*im + 4*quad + r;
        size_t base = ((size_t)b * 256 + m) * N_ + j0 + 64*wc + l15;
        #pragma unroll
        for (int in = 0; in < 4; ++in)
          outp[base + 16 * in] = acc[im][in][r];
      }
  }
}

// ---------------------------------------------------------------------------
// 5) reduce per-block stats partials -> bnp (scale/shift). One block per channel.
// ---------------------------------------------------------------------------
__global__ __launch_bounds__(256) void k_reduce_bn(const float* __restrict__ sp,
                                                   const float* __restrict__ gamma,
                                                   const float* __restrict__ beta,
                                                   float* __restrict__ bnp) {
  int c = blockIdx.x;        // 0..255
  int t = threadIdx.x;
  float s = 0.f, q = 0.f;
  for (int i = t; i < NB_; i += 256) {
    s += sp[(size_t)c * NB_ + i];
    q += sp[(size_t)(256 + c) * NB_ + i];
  }
  #pragma unroll
  for (int off = 32; off >= 1; off >>= 1) {
    s += __shfl_down(s, off, 64);
    q += __shfl_down(q, off, 64);
  }
  __shared__ float ss[4], qq[4];
  if ((t & 63) == 0) { ss[t >> 6] = s; qq[t >> 6] = q; }
  __syncthreads();
  if (t == 0) {
    s = ss[0] + ss[1] + ss[2] + ss[3];
    q = qq[0] + qq[1] + qq[2] + qq[3];
    const float inv = 1.0f / (float)(B_ * N_);
    float mean = s * inv;
    float var  = q * inv - mean * mean;
    float sc = gamma[c] / sqrtf(var + 1e-5f);
    bnp[c] = sc;
    bnp[256 + c] = beta[c] - mean * sc;
  }
}

// ---------------------------------------------------------------------------
// 6) bn1 + relu: h[b][n][256] bf16 -> Xb2[b][n][256] bf16
// ---------------------------------------------------------------------------
__global__ __launch_bounds__(256) void k_bn_relu_cast(const unsigned short* __restrict__ h,
                                                      const float* __restrict__ bnp,
                                                      unsigned short* __restrict__ Xb2) {
  size_t e = (size_t)blockIdx.x * 256 + threadIdx.x;   // ushort4 index
  ushort4 v = ((const ushort4*)h)[e];
  int c0 = (int)((e & 63) << 2);                       // 64 ushort4 per point-row
  float4 sc = *(const float4*)(bnp + c0);
  float4 sh = *(const float4*)(bnp + 256 + c0);
  ushort4 o;
  o.x = f2bf(fmaxf(fmaf(sc.x, bf2f(v.x), sh.x), 0.0f));
  o.y = f2bf(fmaxf(fmaf(sc.y, bf2f(v.y), sh.y), 0.0f));
  o.z = f2bf(fmaxf(fmaf(sc.z, bf2f(v.z), sh.z), 0.0f));
  o.w = f2bf(fmaxf(fmaf(sc.w, bf2f(v.w), sh.w), 0.0f));
  ((ushort4*)Xb2)[e] = o;
}

// ---------------------------------------------------------------------------
// 7) final BN + ReLU in place on d_out [B][H][N]
// ---------------------------------------------------------------------------
__global__ __launch_bounds__(256) void k_bn_relu(float* __restrict__ out,
                                                 const float* __restrict__ bnp) {
  size_t e = (size_t)blockIdx.x * 256 + threadIdx.x;
  float4 v = ((float4*)out)[e];
  int c = (int)((e >> 12) & 255);
  float sc = bnp[c], sh = bnp[256 + c];
  v.x = fmaxf(fmaf(sc, v.x, sh), 0.0f);
  v.y = fmaxf(fmaf(sc, v.y, sh), 0.0f);
  v.z = fmaxf(fmaf(sc, v.z, sh), 0.0f);
  v.w = fmaxf(fmaf(sc, v.w, sh), 0.0f);
  ((float4*)out)[e] = v;
}

// ---------------------------------------------------------------------------
extern "C" void kernel_launch(void* const* d_in, const int* in_sizes, int n_in,
                              void* d_out, int out_size, void* d_ws, size_t ws_size,
                              hipStream_t stream) {
  const float* unknown = (const float*)d_in[0];
  const float* known   = (const float*)d_in[1];
  const float* uf      = (const float*)d_in[2];
  const float* kf      = (const float*)d_in[3];
  const float* W1      = (const float*)d_in[4];
  const float* g1      = (const float*)d_in[5];
  const float* b1      = (const float*)d_in[6];
  const float* W2      = (const float*)d_in[7];
  const float* g2      = (const float*)d_in[8];
  const float* b2      = (const float*)d_in[9];
  float* out = (float*)d_out;

  // workspace layout (~71 MB):
  //   kfT     : B*M*C2 fp32 = 16.8 MB
  //   Xb1     : B*N*K1 bf16 = 48 MB   (alias: part_d/part_i early, Xb2 late)
  //   idx/wgt : 1.6 MB ; Wb : 0.33 MB ; stats_p : 2 MB
  // h (B*N*H bf16, 32 MB) lives in d_out until GEMM2 overwrites it.
  float* ws = (float*)d_ws;
  float*          kfT  = ws;                                          // 4194304 f
  unsigned short* Xb1  = (unsigned short*)(kfT + (size_t)B_*M_*C2_);  // 25165824 us
  float*          part_d = (float*)Xb1;                               // alias (early)
  int*            part_i = (int*)(part_d + (size_t)NC_*B_*3*N_);      // 6.3 MB each
  unsigned short* Xb2  = Xb1;                                         // alias (late)
  int*   idx    = (int*)(Xb1 + (size_t)B_*N_*K1_);
  float* wgt    = (float*)(idx + (size_t)B_*N_*3);
  unsigned short* W1b = (unsigned short*)(wgt + (size_t)B_*N_*3);     // 98304 us
  unsigned short* W2b = W1b + H_*K1_;                                 // 65536 us
  float* stats_p = (float*)(W2b + H_*H_);                             // 524288 f
  float* bnp1   = stats_p + 512 * NB_;
  float* bnp2   = bnp1 + 512;
  float* h      = out;                                                // d_out scratch (bf16)

  k_wcast<<<(H_*K1_ + H_*H_ + 255)/256, 256, 0, stream>>>(W1, W2, W1b);
  k_transpose<<<dim3(M_/32, C2_/32, B_), 256, 0, stream>>>(kf, kfT);
  k_three_nn_part<<<dim3(N_/512, B_, NC_), 256, 0, stream>>>(unknown, known, part_d, part_i);
  k_three_merge<<<dim3(N_/256, B_), 256, 0, stream>>>(part_d, part_i, idx, wgt);
  k_interp<<<dim3(N_/IP_, B_), 256, 0, stream>>>(kfT, idx, wgt, Xb1);
  k_uf_t<<<dim3(N_/32, C1_/32, B_), 256, 0, stream>>>(uf, Xb1);
  k_gemm_mfma<K1_, 0><<<dim3(N_/128, 2, B_), 256, 0, stream>>>(W1b, Xb1, h, stats_p);
  k_reduce_bn<<<256, 256, 0, stream>>>(stats_p, g1, b1, bnp1);
  k_bn_relu_cast<<<(int)((size_t)B_*N_*H_/4/256), 256, 0, stream>>>((unsigned short*)h, bnp1, Xb2);
  k_gemm_mfma<H_, 1><<<dim3(N_/128, 2, B_), 256, 0, stream>>>(W2b, Xb2, out, stats_p);
  k_reduce_bn<<<256, 256, 0, stream>>>(stats_p, g2, b2, bnp2);
  k_bn_relu<<<(int)((size_t)B_*H_*N_/4/256), 256, 0, stream>>>(out, bnp2);
}

// Round 8
// 389.637 us; speedup vs baseline: 1.1622x; 1.1380x over previous
//
#include <hip/hip_runtime.h>
#include <hip/hip_cooperative_groups.h>
#include <math.h>

namespace cg = cooperative_groups;

// Shapes (fixed by the problem)
#define B_   4
#define N_   16384
#define M_   4096
#define C1_  128
#define C2_  256
#define H_   256
#define K1_  384   // C1 + C2

#define NC_  8           // three_nn chunks over M  (DO NOT CHANGE: selection
#define MC_  (M_ / NC_)  //  dynamics are part of the verified numerics)
#define NB_  1024        // GEMM grid blocks (128 * 2 * 4) -> stats partials

typedef unsigned long long u64;
typedef __attribute__((ext_vector_type(8))) short bf16x8;   // 8 bf16 (4 VGPRs)
typedef __attribute__((ext_vector_type(4))) float f32x4;    // mfma acc

__device__ __forceinline__ unsigned short f2bf(float x) {
  unsigned u = __float_as_uint(x);
  return (unsigned short)((u + 0x7FFFu + ((u >> 16) & 1u)) >> 16);  // RNE
}
__device__ __forceinline__ float bf2f(unsigned short u) {
  return __uint_as_float((unsigned)u << 16);
}

// fp32-pair branchless insert (used only in the tiny merge kernel)
__device__ __forceinline__ void ins3(float cd, int ci,
                                     float& d1, int& i1,
                                     float& d2, int& i2,
                                     float& d3, int& i3) {
  bool p3 = cd < d3, p2 = cd < d2, p1 = cd < d1;
  float td = p1 ? d1 : cd; int ti = p1 ? i1 : ci;
  d1 = p1 ? cd : d1;       i1 = p1 ? ci : i1;
  float e3 = p2 ? d2 : cd; int e3i = p2 ? i2 : ci;
  d2 = p2 ? td : d2;       i2 = p2 ? ti : i2;
  d3 = p3 ? e3 : d3;       i3 = p3 ? e3i : i3;
}

// ---------------------------------------------------------------------------
// 1) transpose known_feats [B, C2, M] -> kfT [B, M, C2] fp32 (for gathers)
// ---------------------------------------------------------------------------
__global__ __launch_bounds__(256) void k_transpose(const float* __restrict__ kf,
                                                   float* __restrict__ kfT) {
  __shared__ float tile[32][33];
  int b  = blockIdx.z;
  int i0 = blockIdx.x * 32;
  int c0 = blockIdx.y * 32;
  int tx  = threadIdx.x & 31;
  int tyv = threadIdx.x >> 5;
  const float* src = kf + ((size_t)b * C2_ + c0) * M_ + i0;
  #pragma unroll
  for (int r = 0; r < 32; r += 8)
    tile[tyv + r][tx] = src[(size_t)(tyv + r) * M_ + tx];
  __syncthreads();
  float* dst = kfT + ((size_t)b * M_ + i0) * C2_ + c0;
  #pragma unroll
  for (int r = 0; r < 32; r += 8)
    dst[(size_t)(tyv + r) * C2_ + tx] = tile[tx][tyv + r];
}

// ---------------------------------------------------------------------------
// 2a) three_nn partials — BYTE-EXACT R4 form (LDS staging, NC_=8, t3 guard,
//     branchy insert w/ min+fmed3; HW-verified absmax 0.03125 @104us).
//     DO NOT change selection dynamics (chunking/guard/wave composition).
// ---------------------------------------------------------------------------
__global__ __launch_bounds__(256) void k_three_nn_part(const float* __restrict__ unknown,
                                                       const float* __restrict__ known,
                                                       float* __restrict__ part_d,
                                                       int* __restrict__ part_i) {
  __shared__ float4 sk[MC_];
  int b    = blockIdx.y;
  int ch   = blockIdx.z;
  int base = ch * MC_;
  const float* kb = known + ((size_t)b * M_ + base) * 3;
  for (int i = threadIdx.x; i < MC_; i += 256) {
    float x = kb[3*i+0], y = kb[3*i+1], z = kb[3*i+2];
    sk[i] = make_float4(-2.0f*x, -2.0f*y, -2.0f*z, x*x + y*y + z*z);
  }
  __syncthreads();

  int j = blockIdx.x * 256 + threadIdx.x;
  const float* up = unknown + ((size_t)b * N_ + j) * 3;
  float ux = up[0], uy = up[1], uz = up[2];
  float u2 = ux*ux + uy*uy + uz*uz;

  const float INF = __builtin_inff();
  float d1 = INF, d2 = INF, d3 = INF, t3 = INF;
  int   i1 = 0, i2 = 0, i3 = 0;
  #pragma unroll 4
  for (int i = 0; i < MC_; ++i) {
    float4 k = sk[i];
    float s = fmaf(k.x, ux, fmaf(k.y, uy, fmaf(k.z, uz, k.w)));  // k2 - 2*dot
    if (__any(s < t3)) {
      float d = u2 + s;
      int  gi = base + i;
      bool p3 = d < d3, p2 = d < d2, p1 = d < d1;
      int ni1 = p1 ? gi : i1;
      int ni2 = p1 ? i1 : (p2 ? gi : i2);
      int ni3 = p2 ? i2 : (p3 ? gi : i3);
      float nd1 = fminf(d, d1);
      float nd2 = __builtin_amdgcn_fmed3f(d, d1, d2);
      float nd3 = __builtin_amdgcn_fmed3f(d, d2, d3);
      d1 = nd1; d2 = nd2; d3 = nd3;
      i1 = ni1; i2 = ni2; i3 = ni3;
      t3 = d3 - u2;
    }
  }
  size_t o = ((size_t)(ch * B_ + b) * 3) * N_ + j;
  part_d[o] = d1; part_d[o + N_] = d2; part_d[o + 2*(size_t)N_] = d3;
  part_i[o] = i1; part_i[o + N_] = i2; part_i[o + 2*(size_t)N_] = i3;
}

// ---------------------------------------------------------------------------
// 2b) merge NC partial top-3 lists -> final idx + inverse-distance weights.
// ---------------------------------------------------------------------------
__global__ __launch_bounds__(256) void k_three_merge(const float* __restrict__ part_d,
                                                     const int* __restrict__ part_i,
                                                     int* __restrict__ idx_o,
                                                     float* __restrict__ w_o) {
  int j = blockIdx.x * 256 + threadIdx.x;
  int b = blockIdx.y;
  size_t o0 = ((size_t)b * 3) * N_ + j;
  float d1 = part_d[o0], d2 = part_d[o0 + N_], d3 = part_d[o0 + 2*(size_t)N_];
  int   i1 = part_i[o0], i2 = part_i[o0 + N_], i3 = part_i[o0 + 2*(size_t)N_];
  #pragma unroll
  for (int c = 1; c < NC_; ++c) {
    size_t oc = ((size_t)(c * B_ + b) * 3) * N_ + j;
    #pragma unroll
    for (int k = 0; k < 3; ++k) {
      float cd = part_d[oc + (size_t)k * N_];
      int   ci = part_i[oc + (size_t)k * N_];
      ins3(cd, ci, d1, i1, d2, i2, d3, i3);
    }
  }
  float r1 = 1.0f / (d1 + 1e-8f);
  float r2 = 1.0f / (d2 + 1e-8f);
  float r3 = 1.0f / (d3 + 1e-8f);
  float s  = r1 + r2 + r3;
  size_t o = ((size_t)b * N_ + j) * 3;
  idx_o[o+0] = i1; idx_o[o+1] = i2; idx_o[o+2] = i3;
  w_o[o+0] = r1 / s; w_o[o+1] = r2 / s; w_o[o+2] = r3 / s;
}

// ---------------------------------------------------------------------------
// 3a) three_interpolate -> Xb1[b][j][0:256] bf16 (point-major GEMM operand)
// ---------------------------------------------------------------------------
#define IP_ 32
__global__ __launch_bounds__(256) void k_interp(const float* __restrict__ kfT,
                                                const int* __restrict__ idx,
                                                const float* __restrict__ wgt,
                                                unsigned short* __restrict__ Xb1) {
  int b  = blockIdx.y;
  int j0 = blockIdx.x * IP_;
  const float* kb = kfT + (size_t)b * M_ * C2_;
  int c = threadIdx.x;
  for (int p = 0; p < IP_; ++p) {
    size_t pj = ((size_t)b * N_ + j0 + p) * 3;   // uniform -> scalar loads
    int   i0 = idx[pj+0], i1 = idx[pj+1], i2 = idx[pj+2];
    float w0 = wgt[pj+0], w1 = wgt[pj+1], w2 = wgt[pj+2];
    float v = w0 * kb[(size_t)i0 * C2_ + c]
            + w1 * kb[(size_t)i1 * C2_ + c]
            + w2 * kb[(size_t)i2 * C2_ + c];
    Xb1[((size_t)b * N_ + j0 + p) * K1_ + c] = f2bf(v);
  }
}

// ---------------------------------------------------------------------------
// 3b) transpose+cast unknown_feats [B,C1,N] fp32 -> Xb1[b][j][256+c] bf16
// ---------------------------------------------------------------------------
__global__ __launch_bounds__(256) void k_uf_t(const float* __restrict__ uf,
                                              unsigned short* __restrict__ Xb1) {
  __shared__ float tile[32][33];
  int b  = blockIdx.z;
  int j0 = blockIdx.x * 32;
  int c0 = blockIdx.y * 32;
  int tx = threadIdx.x & 31, ty = threadIdx.x >> 5;
  const float* src = uf + ((size_t)b * C1_ + c0) * N_ + j0;
  #pragma unroll
  for (int r = 0; r < 32; r += 8)
    tile[ty + r][tx] = src[(size_t)(ty + r) * N_ + tx];
  __syncthreads();
  unsigned short* dst = Xb1 + ((size_t)b * N_ + j0) * K1_ + C2_ + c0;
  #pragma unroll
  for (int r = 0; r < 32; r += 8)
    dst[(size_t)(ty + r) * K1_ + tx] = f2bf(tile[tx][ty + r]);
}

// ---------------------------------------------------------------------------
// 3c) cast both weight matrices to bf16 (fused, contiguous dst)
// ---------------------------------------------------------------------------
__global__ void k_wcast(const float* __restrict__ W1, const float* __restrict__ W2,
                        unsigned short* __restrict__ Wb) {
  int i = blockIdx.x * 256 + threadIdx.x;
  int n1 = H_ * K1_, nt = n1 + H_ * H_;
  if (i < nt) Wb[i] = f2bf(i < n1 ? W1[i] : W2[i - n1]);
}

// ===========================================================================
// Split-path kernels (byte-exact R4, HW-verified 387us / absmax 0.03125)
// ===========================================================================
template <int K, int OUTL>
__global__ __launch_bounds__(256) void k_gemm_mfma(const unsigned short* __restrict__ Wb,
                                                   const unsigned short* __restrict__ Xb,
                                                   float* __restrict__ outp,
                                                   float* __restrict__ stats_p) {
  __shared__ float sred[256];
  int t = threadIdx.x;
  sred[t] = 0.0f;
  __syncthreads();

  int b  = blockIdx.z;
  int m0 = blockIdx.y * 128;
  int j0 = blockIdx.x * 128;
  int wid = t >> 6, lane = t & 63;
  int wr = wid >> 1, wc = wid & 1;
  int l15 = lane & 15, quad = lane >> 4;

  const unsigned short* aptr = Wb + (size_t)(m0 + 64*wr + l15) * K + quad * 8;
  const unsigned short* bptr = Xb + ((size_t)b * N_ + j0 + 64*wc + l15) * K + quad * 8;

  f32x4 acc[4][4] = {};
  for (int kt = 0; kt < K; kt += 32) {
    bf16x8 af[4], bfr[4];
    #pragma unroll
    for (int i = 0; i < 4; ++i)
      af[i] = *(const bf16x8*)(aptr + (size_t)(16*i) * K + kt);
    #pragma unroll
    for (int i = 0; i < 4; ++i)
      bfr[i] = *(const bf16x8*)(bptr + (size_t)(16*i) * K + kt);
    #pragma unroll
    for (int im = 0; im < 4; ++im)
      #pragma unroll
      for (int in = 0; in < 4; ++in)
        acc[im][in] = __builtin_amdgcn_mfma_f32_16x16x32_bf16(af[im], bfr[in], acc[im][in], 0, 0, 0);
  }

  #pragma unroll
  for (int im = 0; im < 4; ++im) {
    #pragma unroll
    for (int r = 0; r < 4; ++r) {
      float sv = 0.f, qv = 0.f;
      #pragma unroll
      for (int in = 0; in < 4; ++in) { float v = acc[im][in][r]; sv += v; qv += v * v; }
      #pragma unroll
      for (int off = 1; off < 16; off <<= 1) {
        sv += __shfl_xor(sv, off, 64);
        qv += __shfl_xor(qv, off, 64);
      }
      if (l15 == 0) {
        int ml = 64*wr + 16*im + 4*quad + r;
        atomicAdd(&sred[ml], sv);
        atomicAdd(&sred[128 + ml], qv);
      }
    }
  }
  __syncthreads();
  if (t < 128) {
    int bid = (blockIdx.z * gridDim.y + blockIdx.y) * gridDim.x + blockIdx.x;
    stats_p[(size_t)(m0 + t) * NB_ + bid]       = sred[t];
    stats_p[(size_t)(256 + m0 + t) * NB_ + bid] = sred[128 + t];
  }

  if (OUTL == 0) {
    unsigned short* hp = (unsigned short*)outp;
    #pragma unroll
    for (int in = 0; in < 4; ++in) {
      size_t nrow = (size_t)b * N_ + j0 + 64*wc + 16*in + l15;
      unsigned short* p = hp + nrow * 256 + m0 + 64*wr + quad * 4;
      #pragma unroll
      for (int im = 0; im < 4; ++im) {
        ushort4 o;
        o.x = f2bf(acc[im][in][0]); o.y = f2bf(acc[im][in][1]);
        o.z = f2bf(acc[im][in][2]); o.w = f2bf(acc[im][in][3]);
        *(ushort4*)(p + 16 * im) = o;
      }
    }
  } else {
    #pragma unroll
    for (int im = 0; im < 4; ++im)
      #pragma unroll
      for (int r = 0; r < 4; ++r) {
        int m = m0 + 64*wr + 16*im + 4*quad + r;
        size_t base = ((size_t)b * 256 + m) * N_ + j0 + 64*wc + l15;
        #pragma unroll
        for (int in = 0; in < 4; ++in)
          outp[base + 16 * in] = acc[im][in][r];
      }
  }
}

__global__ __launch_bounds__(256) void k_reduce_bn(const float* __restrict__ sp,
                                                   const float* __restrict__ gamma,
                                                   const float* __restrict__ beta,
                                                   float* __restrict__ bnp) {
  int c = blockIdx.x;
  int t = threadIdx.x;
  float s = 0.f, q = 0.f;
  for (int i = t; i < NB_; i += 256) {
    s += sp[(size_t)c * NB_ + i];
    q += sp[(size_t)(256 + c) * NB_ + i];
  }
  #pragma unroll
  for (int off = 32; off >= 1; off >>= 1) {
    s += __shfl_down(s, off, 64);
    q += __shfl_down(q, off, 64);
  }
  __shared__ float ss[4], qq[4];
  if ((t & 63) == 0) { ss[t >> 6] = s; qq[t >> 6] = q; }
  __syncthreads();
  if (t == 0) {
    s = ss[0] + ss[1] + ss[2] + ss[3];
    q = qq[0] + qq[1] + qq[2] + qq[3];
    const float inv = 1.0f / (float)(B_ * N_);
    float mean = s * inv;
    float var  = q * inv - mean * mean;
    float sc = gamma[c] / sqrtf(var + 1e-5f);
    bnp[c] = sc;
    bnp[256 + c] = beta[c] - mean * sc;
  }
}

__global__ __launch_bounds__(256) void k_bn_relu_cast(const unsigned short* __restrict__ h,
                                                      const float* __restrict__ bnp,
                                                      unsigned short* __restrict__ Xb2) {
  size_t e = (size_t)blockIdx.x * 256 + threadIdx.x;
  ushort4 v = ((const ushort4*)h)[e];
  int c0 = (int)((e & 63) << 2);
  float4 sc = *(const float4*)(bnp + c0);
  float4 sh = *(const float4*)(bnp + 256 + c0);
  ushort4 o;
  o.x = f2bf(fmaxf(fmaf(sc.x, bf2f(v.x), sh.x), 0.0f));
  o.y = f2bf(fmaxf(fmaf(sc.y, bf2f(v.y), sh.y), 0.0f));
  o.z = f2bf(fmaxf(fmaf(sc.z, bf2f(v.z), sh.z), 0.0f));
  o.w = f2bf(fmaxf(fmaf(sc.w, bf2f(v.w), sh.w), 0.0f));
  ((ushort4*)Xb2)[e] = o;
}

__global__ __launch_bounds__(256) void k_bn_relu(float* __restrict__ out,
                                                 const float* __restrict__ bnp) {
  size_t e = (size_t)blockIdx.x * 256 + threadIdx.x;
  float4 v = ((float4*)out)[e];
  int c = (int)((e >> 12) & 255);
  float sc = bnp[c], sh = bnp[256 + c];
  v.x = fmaxf(fmaf(sc, v.x, sh), 0.0f);
  v.y = fmaxf(fmaf(sc, v.y, sh), 0.0f);
  v.z = fmaxf(fmaf(sc, v.z, sh), 0.0f);
  v.w = fmaxf(fmaf(sc, v.w, sh), 0.0f);
  ((float4*)out)[e] = v;
}

// ===========================================================================
// Cooperative fused GEMM + BN + ReLU (3 phases, 2 grid syncs). Identical
// arithmetic/order to the split path everywhere -> bit-identical stats/bnp;
// OUTL 1 output bit-identical (fp32 round trip was lossless); OUTL 0 drops
// one bf16 re-round of h (moves toward the fp32 reference).
// ===========================================================================
template <int K, int OUTL>
__global__ __launch_bounds__(256, 4) void k_gemm_bn(const unsigned short* __restrict__ Wb,
                                                    const unsigned short* __restrict__ Xb,
                                                    float* __restrict__ outp,
                                                    float* __restrict__ stats_p,
                                                    const float* __restrict__ gamma,
                                                    const float* __restrict__ beta,
                                                    float* __restrict__ bnp) {
  __shared__ float sred[256];
  int t = threadIdx.x;
  sred[t] = 0.0f;
  __syncthreads();

  int b  = blockIdx.z;
  int m0 = blockIdx.y * 128;
  int j0 = blockIdx.x * 128;
  int wid = t >> 6, lane = t & 63;
  int wr = wid >> 1, wc = wid & 1;
  int l15 = lane & 15, quad = lane >> 4;

  const unsigned short* aptr = Wb + (size_t)(m0 + 64*wr + l15) * K + quad * 8;
  const unsigned short* bptr = Xb + ((size_t)b * N_ + j0 + 64*wc + l15) * K + quad * 8;

  f32x4 acc[4][4] = {};
  for (int kt = 0; kt < K; kt += 32) {
    bf16x8 af[4], bfr[4];
    #pragma unroll
    for (int i = 0; i < 4; ++i)
      af[i] = *(const bf16x8*)(aptr + (size_t)(16*i) * K + kt);
    #pragma unroll
    for (int i = 0; i < 4; ++i)
      bfr[i] = *(const bf16x8*)(bptr + (size_t)(16*i) * K + kt);
    #pragma unroll
    for (int im = 0; im < 4; ++im)
      #pragma unroll
      for (int in = 0; in < 4; ++in)
        acc[im][in] = __builtin_amdgcn_mfma_f32_16x16x32_bf16(af[im], bfr[in], acc[im][in], 0, 0, 0);
  }

  #pragma unroll
  for (int im = 0; im < 4; ++im) {
    #pragma unroll
    for (int r = 0; r < 4; ++r) {
      float sv = 0.f, qv = 0.f;
      #pragma unroll
      for (int in = 0; in < 4; ++in) { float v = acc[im][in][r]; sv += v; qv += v * v; }
      #pragma unroll
      for (int off = 1; off < 16; off <<= 1) {
        sv += __shfl_xor(sv, off, 64);
        qv += __shfl_xor(qv, off, 64);
      }
      if (l15 == 0) {
        int ml = 64*wr + 16*im + 4*quad + r;
        atomicAdd(&sred[ml], sv);
        atomicAdd(&sred[128 + ml], qv);
      }
    }
  }
  __syncthreads();
  int bid = (blockIdx.z * gridDim.y + blockIdx.y) * gridDim.x + blockIdx.x;
  if (t < 128) {
    stats_p[(size_t)(m0 + t) * NB_ + bid]       = sred[t];
    stats_p[(size_t)(256 + m0 + t) * NB_ + bid] = sred[128 + t];
  }

  cg::this_grid().sync();

  if (bid < 256) {                 // phase 2: block c reduces channel c
    int c = bid;
    float s = 0.f, q = 0.f;
    for (int i = t; i < NB_; i += 256) {
      s += stats_p[(size_t)c * NB_ + i];
      q += stats_p[(size_t)(256 + c) * NB_ + i];
    }
    #pragma unroll
    for (int off = 32; off >= 1; off >>= 1) {
      s += __shfl_down(s, off, 64);
      q += __shfl_down(q, off, 64);
    }
    if ((t & 63) == 0) { sred[t >> 6] = s; sred[8 + (t >> 6)] = q; }
    __syncthreads();
    if (t == 0) {
      s = sred[0] + sred[1] + sred[2] + sred[3];
      q = sred[8] + sred[9] + sred[10] + sred[11];
      const float inv = 1.0f / (float)(B_ * N_);
      float mean = s * inv;
      float var  = q * inv - mean * mean;
      float sc = gamma[c] / sqrtf(var + 1e-5f);
      bnp[c] = sc;
      bnp[256 + c] = beta[c] - mean * sc;
    }
  }

  cg::this_grid().sync();

  float4 sc4[4], sh4[4];
  #pragma unroll
  for (int im = 0; im < 4; ++im) {
    int mb = m0 + 64*wr + 16*im + 4*quad;
    sc4[im] = *(const float4*)(bnp + mb);
    sh4[im] = *(const float4*)(bnp + 256 + mb);
  }
  if (OUTL == 0) {
    unsigned short* hp = (unsigned short*)outp;   // Xb2 bf16 [b][n][256]
    #pragma unroll
    for (int in = 0; in < 4; ++in) {
      size_t nrow = (size_t)b * N_ + j0 + 64*wc + 16*in + l15;
      unsigned short* p = hp + nrow * 256 + m0 + 64*wr + quad * 4;
      #pragma unroll
      for (int im = 0; im < 4; ++im) {
        ushort4 o;
        o.x = f2bf(fmaxf(fmaf(sc4[im].x, acc[im][in][0], sh4[im].x), 0.0f));
        o.y = f2bf(fmaxf(fmaf(sc4[im].y, acc[im][in][1], sh4[im].y), 0.0f));
        o.z = f2bf(fmaxf(fmaf(sc4[im].z, acc[im][in][2], sh4[im].z), 0.0f));
        o.w = f2bf(fmaxf(fmaf(sc4[im].w, acc[im][in][3], sh4[im].w), 0.0f));
        *(ushort4*)(p + 16 * im) = o;
      }
    }
  } else {
    #pragma unroll
    for (int im = 0; im < 4; ++im) {
      #pragma unroll
      for (int r = 0; r < 4; ++r) {
        int m = m0 + 64*wr + 16*im + 4*quad + r;
        float sc = (r == 0) ? sc4[im].x : (r == 1) ? sc4[im].y : (r == 2) ? sc4[im].z : sc4[im].w;
        float sh = (r == 0) ? sh4[im].x : (r == 1) ? sh4[im].y : (r == 2) ? sh4[im].z : sh4[im].w;
        size_t base = ((size_t)b * 256 + m) * N_ + j0 + 64*wc + l15;
        #pragma unroll
        for (int in = 0; in < 4; ++in)
          outp[base + 16 * in] = fmaxf(fmaf(sc, acc[im][in][r], sh), 0.0f);
      }
    }
  }
}

// ---------------------------------------------------------------------------
// path memo: -1 undecided, 0 split (verified R4), 1 cooperative fused.
// Decided once on the first (non-captured) call via host queries + a
// return-code-checked trial; later (captured) calls replay the decision.
// ---------------------------------------------------------------------------
static int g_path = -1;

extern "C" void kernel_launch(void* const* d_in, const int* in_sizes, int n_in,
                              void* d_out, int out_size, void* d_ws, size_t ws_size,
                              hipStream_t stream) {
  const float* unknown = (const float*)d_in[0];
  const float* known   = (const float*)d_in[1];
  const float* uf      = (const float*)d_in[2];
  const float* kf      = (const float*)d_in[3];
  const float* W1      = (const float*)d_in[4];
  const float* g1      = (const float*)d_in[5];
  const float* b1      = (const float*)d_in[6];
  const float* W2      = (const float*)d_in[7];
  const float* g2      = (const float*)d_in[8];
  const float* b2      = (const float*)d_in[9];
  float* out = (float*)d_out;

  float* ws = (float*)d_ws;
  float*          kfT  = ws;
  unsigned short* Xb1  = (unsigned short*)(kfT + (size_t)B_*M_*C2_);
  float*          part_d = (float*)Xb1;                               // alias (early)
  int*            part_i = (int*)(part_d + (size_t)NC_*B_*3*N_);
  unsigned short* Xb2  = Xb1;                                         // alias (late)
  int*   idx    = (int*)(Xb1 + (size_t)B_*N_*K1_);
  float* wgt    = (float*)(idx + (size_t)B_*N_*3);
  unsigned short* W1b = (unsigned short*)(wgt + (size_t)B_*N_*3);
  unsigned short* W2b = W1b + H_*K1_;
  float* stats_p = (float*)(W2b + H_*H_);
  float* bnp1   = stats_p + 512 * NB_;
  float* bnp2   = bnp1 + 512;
  float* h      = out;                       // d_out scratch (bf16), split path only

  k_wcast<<<(H_*K1_ + H_*H_ + 255)/256, 256, 0, stream>>>(W1, W2, W1b);
  k_transpose<<<dim3(M_/32, C2_/32, B_), 256, 0, stream>>>(kf, kfT);
  k_three_nn_part<<<dim3(N_/256, B_, NC_), 256, 0, stream>>>(unknown, known, part_d, part_i);
  k_three_merge<<<dim3(N_/256, B_), 256, 0, stream>>>(part_d, part_i, idx, wgt);
  k_interp<<<dim3(N_/IP_, B_), 256, 0, stream>>>(kfT, idx, wgt, Xb1);
  k_uf_t<<<dim3(N_/32, C1_/32, B_), 256, 0, stream>>>(uf, Xb1);

  if (g_path == -1) {
    // host-side queries only (no stream side-effects; graph-safe, but this
    // branch runs on the first, non-captured call anyway)
    int dev = 0;
    (void)hipGetDevice(&dev);
    int coop = 0;
    (void)hipDeviceGetAttribute(&coop, hipDeviceAttributeCooperativeLaunch, dev);
    int occ1 = 0, occ2 = 0;
    (void)hipOccupancyMaxActiveBlocksPerMultiprocessor(&occ1, (const void*)k_gemm_bn<K1_, 0>, 256, 0);
    (void)hipOccupancyMaxActiveBlocksPerMultiprocessor(&occ2, (const void*)k_gemm_bn<H_, 1>, 256, 0);
    g_path = (coop != 0 && occ1 >= 4 && occ2 >= 4) ? 1 : 0;
  }

  bool fused_done = false;
  if (g_path == 1) {
    const unsigned short* aW1 = W1b; const unsigned short* aX1 = Xb1;
    float* aO1 = (float*)Xb2; float* aS = stats_p;
    const float* aG1 = g1; const float* aB1 = b1; float* aP1 = bnp1;
    void* args1[] = { &aW1, &aX1, &aO1, &aS, &aG1, &aB1, &aP1 };
    hipError_t e1 = hipLaunchCooperativeKernel((const void*)k_gemm_bn<K1_, 0>,
                                               dim3(N_/128, 2, B_), dim3(256), args1, 0, stream);
    if (e1 == hipSuccess) {
      const unsigned short* aW2 = W2b; const unsigned short* aX2 = Xb2;
      float* aO2 = out;
      const float* aG2 = g2; const float* aB2 = b2; float* aP2 = bnp2;
      void* args2[] = { &aW2, &aX2, &aO2, &aS, &aG2, &aB2, &aP2 };
      hipError_t e2 = hipLaunchCooperativeKernel((const void*)k_gemm_bn<H_, 1>,
                                                 dim3(N_/128, 2, B_), dim3(256), args2, 0, stream);
      if (e2 == hipSuccess) {
        fused_done = true;
      } else {
        // stage-1 fused already enqueued (produces Xb2 + bnp1); finish stage 2 split
        g_path = 0;
        k_gemm_mfma<H_, 1><<<dim3(N_/128, 2, B_), 256, 0, stream>>>(W2b, Xb2, out, stats_p);
        k_reduce_bn<<<256, 256, 0, stream>>>(stats_p, g2, b2, bnp2);
        k_bn_relu<<<(int)((size_t)B_*H_*N_/4/256), 256, 0, stream>>>(out, bnp2);
        fused_done = true;
      }
    } else {
      g_path = 0;   // fall through to full split below
    }
  }

  if (!fused_done) {
    k_gemm_mfma<K1_, 0><<<dim3(N_/128, 2, B_), 256, 0, stream>>>(W1b, Xb1, h, stats_p);
    k_reduce_bn<<<256, 256, 0, stream>>>(stats_p, g1, b1, bnp1);
    k_bn_relu_cast<<<(int)((size_t)B_*N_*H_/4/256), 256, 0, stream>>>((unsigned short*)h, bnp1, Xb2);
    k_gemm_mfma<H_, 1><<<dim3(N_/128, 2, B_), 256, 0, stream>>>(W2b, Xb2, out, stats_p);
    k_reduce_bn<<<256, 256, 0, stream>>>(stats_p, g2, b2, bnp2);
    k_bn_relu<<<(int)((size_t)B_*H_*N_/4/256), 256, 0, stream>>>(out, bnp2);
  }
}

// Round 9
// 340.961 us; speedup vs baseline: 1.3281x; 1.1428x over previous
//
#include <hip/hip_runtime.h>
#include <math.h>

// Shapes (fixed by the problem)
#define B_   4
#define N_   16384
#define M_   4096
#define C1_  128
#define C2_  256
#define H_   256
#define K1_  384   // C1 + C2

#define NC_  8           // three_nn chunks over M  (DO NOT CHANGE: selection
#define MC_  (M_ / NC_)  //  dynamics are part of the verified numerics)
#define NB_  1024        // GEMM grid blocks (128 * 2 * 4) -> stats partials

typedef unsigned long long u64;
typedef __attribute__((ext_vector_type(8))) short bf16x8;   // 8 bf16 (4 VGPRs)
typedef __attribute__((ext_vector_type(4))) float f32x4;    // mfma acc

typedef const __attribute__((address_space(1))) unsigned int* gptr_t;
typedef __attribute__((address_space(3))) unsigned int* lptr_t;

__device__ __forceinline__ unsigned short f2bf(float x) {
  unsigned u = __float_as_uint(x);
  return (unsigned short)((u + 0x7FFFu + ((u >> 16) & 1u)) >> 16);  // RNE
}
__device__ __forceinline__ float bf2f(unsigned short u) {
  return __uint_as_float((unsigned)u << 16);
}

// fp32-pair branchless insert (merge phase only)
__device__ __forceinline__ void ins3(float cd, int ci,
                                     float& d1, int& i1,
                                     float& d2, int& i2,
                                     float& d3, int& i3) {
  bool p3 = cd < d3, p2 = cd < d2, p1 = cd < d1;
  float td = p1 ? d1 : cd; int ti = p1 ? i1 : ci;
  d1 = p1 ? cd : d1;       i1 = p1 ? ci : i1;
  float e3 = p2 ? d2 : cd; int e3i = p2 ? i2 : ci;
  d2 = p2 ? td : d2;       i2 = p2 ? ti : i2;
  d3 = p3 ? e3 : d3;       i3 = p3 ? e3i : i3;
}

// ---------------------------------------------------------------------------
// 1) pre1: transpose known_feats [B,C2,M] -> kfT [B,M,C2]  (z = 0..3)
//          + cast W1/W2 -> bf16 Wb                          (z = 4)
// ---------------------------------------------------------------------------
__global__ __launch_bounds__(256) void k_pre1(const float* __restrict__ kf,
                                              float* __restrict__ kfT,
                                              const float* __restrict__ W1,
                                              const float* __restrict__ W2,
                                              unsigned short* __restrict__ Wb) {
  if (blockIdx.z == 4) {
    int id = blockIdx.y * 128 + blockIdx.x;            // 0..1023
    int i  = id * 256 + threadIdx.x;
    int n1 = H_ * K1_, nt = n1 + H_ * H_;
    if (i < nt) Wb[i] = f2bf(i < n1 ? W1[i] : W2[i - n1]);
    return;
  }
  __shared__ float tile[32][33];
  int b  = blockIdx.z;
  int i0 = blockIdx.x * 32;
  int c0 = blockIdx.y * 32;
  int tx  = threadIdx.x & 31;
  int tyv = threadIdx.x >> 5;
  const float* src = kf + ((size_t)b * C2_ + c0) * M_ + i0;
  #pragma unroll
  for (int r = 0; r < 32; r += 8)
    tile[tyv + r][tx] = src[(size_t)(tyv + r) * M_ + tx];
  __syncthreads();
  float* dst = kfT + ((size_t)b * M_ + i0) * C2_ + c0;
  #pragma unroll
  for (int r = 0; r < 32; r += 8)
    dst[(size_t)(tyv + r) * C2_ + tx] = tile[tx][tyv + r];
}

// ---------------------------------------------------------------------------
// 2) three_nn partials — BYTE-EXACT R4 form (LDS staging, NC_=8, t3 guard,
//    branchy insert w/ min+fmed3; HW-verified absmax 0.03125 @104us).
//    DO NOT change selection dynamics (chunking/guard/wave composition).
//    part_d/part_i now live in d_out scratch (consumed by k_pre2 before
//    GEMM1 reuses d_out for h).
// ---------------------------------------------------------------------------
__global__ __launch_bounds__(256) void k_three_nn_part(const float* __restrict__ unknown,
                                                       const float* __restrict__ known,
                                                       float* __restrict__ part_d,
                                                       int* __restrict__ part_i) {
  __shared__ float4 sk[MC_];
  int b    = blockIdx.y;
  int ch   = blockIdx.z;
  int base = ch * MC_;
  const float* kb = known + ((size_t)b * M_ + base) * 3;
  for (int i = threadIdx.x; i < MC_; i += 256) {
    float x = kb[3*i+0], y = kb[3*i+1], z = kb[3*i+2];
    sk[i] = make_float4(-2.0f*x, -2.0f*y, -2.0f*z, x*x + y*y + z*z);
  }
  __syncthreads();

  int j = blockIdx.x * 256 + threadIdx.x;
  const float* up = unknown + ((size_t)b * N_ + j) * 3;
  float ux = up[0], uy = up[1], uz = up[2];
  float u2 = ux*ux + uy*uy + uz*uz;

  const float INF = __builtin_inff();
  float d1 = INF, d2 = INF, d3 = INF, t3 = INF;
  int   i1 = 0, i2 = 0, i3 = 0;
  #pragma unroll 4
  for (int i = 0; i < MC_; ++i) {
    float4 k = sk[i];
    float s = fmaf(k.x, ux, fmaf(k.y, uy, fmaf(k.z, uz, k.w)));  // k2 - 2*dot
    if (__any(s < t3)) {
      float d = u2 + s;
      int  gi = base + i;
      bool p3 = d < d3, p2 = d < d2, p1 = d < d1;
      int ni1 = p1 ? gi : i1;
      int ni2 = p1 ? i1 : (p2 ? gi : i2);
      int ni3 = p2 ? i2 : (p3 ? gi : i3);
      float nd1 = fminf(d, d1);
      float nd2 = __builtin_amdgcn_fmed3f(d, d1, d2);
      float nd3 = __builtin_amdgcn_fmed3f(d, d2, d3);
      d1 = nd1; d2 = nd2; d3 = nd3;
      i1 = ni1; i2 = ni2; i3 = ni3;
      t3 = d3 - u2;
    }
  }
  size_t o = ((size_t)(ch * B_ + b) * 3) * N_ + j;
  part_d[o] = d1; part_d[o + N_] = d2; part_d[o + 2*(size_t)N_] = d3;
  part_i[o] = i1; part_i[o + N_] = i2; part_i[o + 2*(size_t)N_] = i3;
}

// ---------------------------------------------------------------------------
// 3) pre2: fused {merge + three_interpolate} (y==4) and uf_t (y<4).
//    merge runs per-point in threads 0..31 with the VERBATIM ins3 chain and
//    weight arithmetic of the old k_three_merge -> bit-identical idx/weights
//    (kept in LDS; the global idx/wgt buffers and their traffic are gone).
//    interp & uf_t bodies are verbatim -> Xb1 bits unchanged.
// ---------------------------------------------------------------------------
__global__ __launch_bounds__(256) void k_pre2(const float* __restrict__ part_d,
                                              const int* __restrict__ part_i,
                                              const float* __restrict__ kfT,
                                              const float* __restrict__ uf,
                                              unsigned short* __restrict__ Xb1) {
  int b = blockIdx.z;
  if (blockIdx.y < 4) {
    // ---- uf_t: transpose+cast unknown_feats [B,C1,N] -> Xb1[b][j][256+c]
    __shared__ float tile[32][33];
    int j0 = blockIdx.x * 32;
    int c0 = blockIdx.y * 32;
    int tx = threadIdx.x & 31, ty = threadIdx.x >> 5;
    const float* src = uf + ((size_t)b * C1_ + c0) * N_ + j0;
    #pragma unroll
    for (int r = 0; r < 32; r += 8)
      tile[ty + r][tx] = src[(size_t)(ty + r) * N_ + tx];
    __syncthreads();
    unsigned short* dst = Xb1 + ((size_t)b * N_ + j0) * K1_ + C2_ + c0;
    #pragma unroll
    for (int r = 0; r < 32; r += 8)
      dst[(size_t)(ty + r) * K1_ + tx] = f2bf(tile[tx][ty + r]);
    return;
  }
  // ---- merge (threads 0..31, one point each) + interp (all 256 threads)
  __shared__ float lw[32][3];
  __shared__ int   li[32][3];
  int t  = threadIdx.x;
  int j0 = blockIdx.x * 32;
  if (t < 32) {
    int j = j0 + t;
    size_t o0 = ((size_t)b * 3) * N_ + j;
    float d1 = part_d[o0], d2 = part_d[o0 + N_], d3 = part_d[o0 + 2*(size_t)N_];
    int   i1 = part_i[o0], i2 = part_i[o0 + N_], i3 = part_i[o0 + 2*(size_t)N_];
    #pragma unroll
    for (int c = 1; c < NC_; ++c) {
      size_t oc = ((size_t)(c * B_ + b) * 3) * N_ + j;
      #pragma unroll
      for (int k = 0; k < 3; ++k) {
        float cd = part_d[oc + (size_t)k * N_];
        int   ci = part_i[oc + (size_t)k * N_];
        ins3(cd, ci, d1, i1, d2, i2, d3, i3);
      }
    }
    float r1 = 1.0f / (d1 + 1e-8f);
    float r2 = 1.0f / (d2 + 1e-8f);
    float r3 = 1.0f / (d3 + 1e-8f);
    float s  = r1 + r2 + r3;
    li[t][0] = i1; li[t][1] = i2; li[t][2] = i3;
    lw[t][0] = r1 / s; lw[t][1] = r2 / s; lw[t][2] = r3 / s;
  }
  __syncthreads();
  const float* kb = kfT + (size_t)b * M_ * C2_;
  int c = t;
  for (int p = 0; p < 32; ++p) {
    int   i0 = li[p][0], i1 = li[p][1], i2 = li[p][2];
    float w0 = lw[p][0], w1 = lw[p][1], w2 = lw[p][2];
    float v = w0 * kb[(size_t)i0 * C2_ + c]
            + w1 * kb[(size_t)i1 * C2_ + c]
            + w2 * kb[(size_t)i2 * C2_ + c];
    Xb1[((size_t)b * N_ + j0 + p) * K1_ + c] = f2bf(v);
  }
}

// ---------------------------------------------------------------------------
// 4) bf16 MFMA GEMM with global_load_lds-staged [128][32] A/B tiles (m97
//    structure). MFMA fragment set, kt order, stats reduction and store
//    addresses are IDENTICAL to the verified R4 kernel -> outputs and stats
//    bit-identical; only the operand path (global->LDS->regs, each element
//    loaded once per block instead of twice, 16B async) changed.
//    Staging map per wave-instruction: lane i -> lds base + i*16B, which
//    equals row (i>>2)*64B + (i&3)*16B of the row-major [16][32]bf16 chunk,
//    so the per-lane GLOBAL address (m0+16c+(i>>2), kt+(i&3)*8) matches the
//    linear LDS dest exactly (guide m104: dest is wave-uniform + lane*size).
//    OUTL 0: write h[b][n][m] bf16 ; OUTL 1: write out[b][m][n] fp32.
// ---------------------------------------------------------------------------
template <int K, int OUTL>
__global__ __launch_bounds__(256) void k_gemm_mfma(const unsigned short* __restrict__ Wb,
                                                   const unsigned short* __restrict__ Xb,
                                                   float* __restrict__ outp,
                                                   float* __restrict__ stats_p) {
  __shared__ float sred[256];
  __shared__ unsigned short lA[4096];   // [128][32] bf16 = 8 KB
  __shared__ unsigned short lB[4096];
  int t = threadIdx.x;
  sred[t] = 0.0f;
  __syncthreads();

  int b  = blockIdx.z;
  int m0 = blockIdx.y * 128;
  int j0 = blockIdx.x * 128;
  int wid = t >> 6, lane = t & 63;
  int wr = wid >> 1, wc = wid & 1;
  int l15 = lane & 15, quad = lane >> 4;

  // staging addresses: wave wid stages chunks c0,c1 (16 rows each) of A and B
  int srow = lane >> 2;
  int scol = (lane & 3) * 8;
  int c0 = wid * 2, c1 = wid * 2 + 1;
  const unsigned short* gA0 = Wb + (size_t)(m0 + c0*16 + srow) * K + scol;
  const unsigned short* gA1 = Wb + (size_t)(m0 + c1*16 + srow) * K + scol;
  const unsigned short* gB0 = Xb + ((size_t)b * N_ + j0 + c0*16 + srow) * K + scol;
  const unsigned short* gB1 = Xb + ((size_t)b * N_ + j0 + c1*16 + srow) * K + scol;
  unsigned short* sA0 = lA + c0 * 512;
  unsigned short* sA1 = lA + c1 * 512;
  unsigned short* sB0 = lB + c0 * 512;
  unsigned short* sB1 = lB + c1 * 512;

  const unsigned short* fA = lA + (64*wr + l15) * 32 + quad * 8;
  const unsigned short* fB = lB + (64*wc + l15) * 32 + quad * 8;

  f32x4 acc[4][4] = {};
  for (int kt = 0; kt < K; kt += 32) {
    __builtin_amdgcn_global_load_lds((gptr_t)(gA0 + kt), (lptr_t)sA0, 16, 0, 0);
    __builtin_amdgcn_global_load_lds((gptr_t)(gA1 + kt), (lptr_t)sA1, 16, 0, 0);
    __builtin_amdgcn_global_load_lds((gptr_t)(gB0 + kt), (lptr_t)sB0, 16, 0, 0);
    __builtin_amdgcn_global_load_lds((gptr_t)(gB1 + kt), (lptr_t)sB1, 16, 0, 0);
    __syncthreads();                              // vmcnt(0) drain + barrier
    bf16x8 af[4], bfr[4];
    #pragma unroll
    for (int i = 0; i < 4; ++i)
      af[i] = *(const bf16x8*)(fA + i * 512);     // 16 rows * 32 cols
    #pragma unroll
    for (int i = 0; i < 4; ++i)
      bfr[i] = *(const bf16x8*)(fB + i * 512);
    #pragma unroll
    for (int im = 0; im < 4; ++im)
      #pragma unroll
      for (int in = 0; in < 4; ++in)
        acc[im][in] = __builtin_amdgcn_mfma_f32_16x16x32_bf16(af[im], bfr[in], acc[im][in], 0, 0, 0);
    __syncthreads();                              // reads done before next store
  }

  // --- BN statistics: shuffle-reduce over 16 n-lanes, combine in LDS ---
  #pragma unroll
  for (int im = 0; im < 4; ++im) {
    #pragma unroll
    for (int r = 0; r < 4; ++r) {
      float sv = 0.f, qv = 0.f;
      #pragma unroll
      for (int in = 0; in < 4; ++in) { float v = acc[im][in][r]; sv += v; qv += v * v; }
      #pragma unroll
      for (int off = 1; off < 16; off <<= 1) {
        sv += __shfl_xor(sv, off, 64);
        qv += __shfl_xor(qv, off, 64);
      }
      if (l15 == 0) {
        int ml = 64*wr + 16*im + 4*quad + r;
        atomicAdd(&sred[ml], sv);                 // 2-way max, commutative
        atomicAdd(&sred[128 + ml], qv);
      }
    }
  }
  __syncthreads();
  if (t < 128) {
    int bid = (blockIdx.z * gridDim.y + blockIdx.y) * gridDim.x + blockIdx.x;
    stats_p[(size_t)(m0 + t) * NB_ + bid]       = sred[t];
    stats_p[(size_t)(256 + m0 + t) * NB_ + bid] = sred[128 + t];
  }

  // --- store ---
  if (OUTL == 0) {
    unsigned short* hp = (unsigned short*)outp;   // h bf16 [b][n][256]
    #pragma unroll
    for (int in = 0; in < 4; ++in) {
      size_t nrow = (size_t)b * N_ + j0 + 64*wc + 16*in + l15;
      unsigned short* p = hp + nrow * 256 + m0 + 64*wr + quad * 4;
      #pragma unroll
      for (int im = 0; im < 4; ++im) {
        ushort4 o;
        o.x = f2bf(acc[im][in][0]); o.y = f2bf(acc[im][in][1]);
        o.z = f2bf(acc[im][in][2]); o.w = f2bf(acc[im][in][3]);
        *(ushort4*)(p + 16 * im) = o;
      }
    }
  } else {
    #pragma unroll
    for (int im = 0; im < 4; ++im)
      #pragma unroll
      for (int r = 0; r < 4; ++r) {
        int m = m0 + 64*wr + 16*im + 4*quad + r;
        size_t base = ((size_t)b * 256 + m) * N_ + j0 + 64*wc + l15;
        #pragma unroll
        for (int in = 0; in < 4; ++in)
          outp[base + 16 * in] = acc[im][in][r];
      }
  }
}

// ---------------------------------------------------------------------------
// 5) reduce per-block stats partials -> bnp (scale/shift). One block/channel.
// ---------------------------------------------------------------------------
__global__ __launch_bounds__(256) void k_reduce_bn(const float* __restrict__ sp,
                                                   const float* __restrict__ gamma,
                                                   const float* __restrict__ beta,
                                                   float* __restrict__ bnp) {
  int c = blockIdx.x;
  int t = threadIdx.x;
  float s = 0.f, q = 0.f;
  for (int i = t; i < NB_; i += 256) {
    s += sp[(size_t)c * NB_ + i];
    q += sp[(size_t)(256 + c) * NB_ + i];
  }
  #pragma unroll
  for (int off = 32; off >= 1; off >>= 1) {
    s += __shfl_down(s, off, 64);
    q += __shfl_down(q, off, 64);
  }
  __shared__ float ss[4], qq[4];
  if ((t & 63) == 0) { ss[t >> 6] = s; qq[t >> 6] = q; }
  __syncthreads();
  if (t == 0) {
    s = ss[0] + ss[1] + ss[2] + ss[3];
    q = qq[0] + qq[1] + qq[2] + qq[3];
    const float inv = 1.0f / (float)(B_ * N_);
    float mean = s * inv;
    float var  = q * inv - mean * mean;
    float sc = gamma[c] / sqrtf(var + 1e-5f);
    bnp[c] = sc;
    bnp[256 + c] = beta[c] - mean * sc;
  }
}

// ---------------------------------------------------------------------------
// 6) bn1 + relu: h[b][n][256] bf16 -> Xb2[b][n][256] bf16
// ---------------------------------------------------------------------------
__global__ __launch_bounds__(256) void k_bn_relu_cast(const unsigned short* __restrict__ h,
                                                      const float* __restrict__ bnp,
                                                      unsigned short* __restrict__ Xb2) {
  size_t e = (size_t)blockIdx.x * 256 + threadIdx.x;   // ushort4 index
  ushort4 v = ((const ushort4*)h)[e];
  int c0 = (int)((e & 63) << 2);
  float4 sc = *(const float4*)(bnp + c0);
  float4 sh = *(const float4*)(bnp + 256 + c0);
  ushort4 o;
  o.x = f2bf(fmaxf(fmaf(sc.x, bf2f(v.x), sh.x), 0.0f));
  o.y = f2bf(fmaxf(fmaf(sc.y, bf2f(v.y), sh.y), 0.0f));
  o.z = f2bf(fmaxf(fmaf(sc.z, bf2f(v.z), sh.z), 0.0f));
  o.w = f2bf(fmaxf(fmaf(sc.w, bf2f(v.w), sh.w), 0.0f));
  ((ushort4*)Xb2)[e] = o;
}

// ---------------------------------------------------------------------------
// 7) final BN + ReLU in place on d_out [B][H][N]
// ---------------------------------------------------------------------------
__global__ __launch_bounds__(256) void k_bn_relu(float* __restrict__ out,
                                                 const float* __restrict__ bnp) {
  size_t e = (size_t)blockIdx.x * 256 + threadIdx.x;
  float4 v = ((float4*)out)[e];
  int c = (int)((e >> 12) & 255);
  float sc = bnp[c], sh = bnp[256 + c];
  v.x = fmaxf(fmaf(sc, v.x, sh), 0.0f);
  v.y = fmaxf(fmaf(sc, v.y, sh), 0.0f);
  v.z = fmaxf(fmaf(sc, v.z, sh), 0.0f);
  v.w = fmaxf(fmaf(sc, v.w, sh), 0.0f);
  ((float4*)out)[e] = v;
}

// ---------------------------------------------------------------------------
extern "C" void kernel_launch(void* const* d_in, const int* in_sizes, int n_in,
                              void* d_out, int out_size, void* d_ws, size_t ws_size,
                              hipStream_t stream) {
  const float* unknown = (const float*)d_in[0];
  const float* known   = (const float*)d_in[1];
  const float* uf      = (const float*)d_in[2];
  const float* kf      = (const float*)d_in[3];
  const float* W1      = (const float*)d_in[4];
  const float* g1      = (const float*)d_in[5];
  const float* b1      = (const float*)d_in[6];
  const float* W2      = (const float*)d_in[7];
  const float* g2      = (const float*)d_in[8];
  const float* b2      = (const float*)d_in[9];
  float* out = (float*)d_out;

  // workspace (~69 MB): kfT 16.8MB | Xb1 48MB (alias Xb2 late) | Wb 0.33MB
  //                     | stats_p 2MB | bnp1/bnp2
  // d_out (64MB) scratch timeline: part_d/part_i (12.6MB, three_nn -> pre2)
  //   -> h bf16 (32MB, GEMM1 -> bn_relu_cast) -> final out fp32 (GEMM2+).
  float* ws = (float*)d_ws;
  float*          kfT  = ws;
  unsigned short* Xb1  = (unsigned short*)(kfT + (size_t)B_*M_*C2_);
  unsigned short* Xb2  = Xb1;                                         // alias (late)
  unsigned short* W1b  = Xb1 + (size_t)B_*N_*K1_;
  unsigned short* W2b  = W1b + H_*K1_;
  float* stats_p = (float*)(W2b + H_*H_);
  float* bnp1   = stats_p + 512 * NB_;
  float* bnp2   = bnp1 + 512;
  float* part_d = out;                                                // d_out scratch
  int*   part_i = (int*)(part_d + (size_t)NC_*B_*3*N_);
  float* h      = out;                                                // d_out scratch (bf16)

  k_pre1<<<dim3(M_/32, C2_/32, 5), 256, 0, stream>>>(kf, kfT, W1, W2, W1b);
  k_three_nn_part<<<dim3(N_/256, B_, NC_), 256, 0, stream>>>(unknown, known, part_d, part_i);
  k_pre2<<<dim3(N_/32, 5, B_), 256, 0, stream>>>(part_d, part_i, kfT, uf, Xb1);
  k_gemm_mfma<K1_, 0><<<dim3(N_/128, 2, B_), 256, 0, stream>>>(W1b, Xb1, h, stats_p);
  k_reduce_bn<<<256, 256, 0, stream>>>(stats_p, g1, b1, bnp1);
  k_bn_relu_cast<<<(int)((size_t)B_*N_*H_/4/256), 256, 0, stream>>>((unsigned short*)h, bnp1, Xb2);
  k_gemm_mfma<H_, 1><<<dim3(N_/128, 2, B_), 256, 0, stream>>>(W2b, Xb2, out, stats_p);
  k_reduce_bn<<<256, 256, 0, stream>>>(stats_p, g2, b2, bnp2);
  k_bn_relu<<<(int)((size_t)B_*H_*N_/4/256), 256, 0, stream>>>(out, bnp2);
}